// Round 12
// baseline (68.789 us; speedup 1.0000x reference)
//
#include <hip/hip_runtime.h>
#include <hip/hip_bf16.h>
#include <stdint.h>

// MoEDecoder: B=64,T=256,IN=256,HID=512,OUT=256,L=2,E=16,S=1
// R12: LDS-port relief. B (weights, zero reuse) now loads DIRECTLY to
// registers (global dwordx4, dbuf, depth-2 counted vmcnt) — no glds, no
// B ds_reads. LDS holds only h (A operand, 8x reuse) at HPAD=520.
// 8 waves x 64-token slab, grid 256, barrier-free K-loop, XCD swizzle.
// Per-CU LDS traffic/step: 96KB -> 32KB; staging LDS freed (64KB total).

typedef __attribute__((ext_vector_type(8))) short bf16x8;
typedef __attribute__((ext_vector_type(4))) float f32x4;

#define HPAD 520  // h row stride: 1040B -> 4-bank row stagger, 2-way (free)
#define VMWAIT(N) asm volatile("s_waitcnt vmcnt(" #N ")" ::: "memory")

static __device__ __forceinline__ uint16_t f2bf(float f) {
  union { float f; uint32_t u; } c; c.f = f;
  uint32_t r = (c.u + 0x7FFFu + ((c.u >> 16) & 1u)) >> 16;
  return (uint16_t)r;
}
static __device__ __forceinline__ float bf2f(uint16_t h) {
  union { uint32_t u; float f; } c; c.u = ((uint32_t)h) << 16;
  return c.f;
}

// ---- merged pre-pass: Wc=Ws+Wr (bf16), Wi/Wo bf16, bc=bs+br ----
__global__ __launch_bounds__(256) void k_prep(
    const float* __restrict__ Ws, const float* __restrict__ Wr,
    const float* __restrict__ Wi, const float* __restrict__ Wo,
    const float* __restrict__ bs, const float* __restrict__ br,
    uint16_t* __restrict__ Wcb, uint16_t* __restrict__ Wib,
    uint16_t* __restrict__ Wob, float* __restrict__ bc) {
  int bid = blockIdx.x, tid = threadIdx.x;
  if (bid < 8192) {                       // combine_w: 2*16*512*512 / 4
    int i = bid * 256 + tid;
    int idx = i * 4;
    int l = idx >> 22;
    int within = idx & (262144 - 1);
    float4 a = *(const float4*)(Ws + l * 262144 + within);
    float4 b = *(const float4*)(Wr + idx);
    ushort4 o;
    o.x = f2bf(a.x + b.x); o.y = f2bf(a.y + b.y);
    o.z = f2bf(a.z + b.z); o.w = f2bf(a.w + b.w);
    ((ushort4*)Wcb)[i] = o;
  } else if (bid < 8320) {                // Wi: 512*256/4
    int i = (bid - 8192) * 256 + tid;
    float4 v = ((const float4*)Wi)[i];
    ushort4 o;
    o.x = f2bf(v.x); o.y = f2bf(v.y); o.z = f2bf(v.z); o.w = f2bf(v.w);
    ((ushort4*)Wib)[i] = o;
  } else if (bid < 8448) {                // Wo: 256*512/4
    int i = (bid - 8320) * 256 + tid;
    float4 v = ((const float4*)Wo)[i];
    ushort4 o;
    o.x = f2bf(v.x); o.y = f2bf(v.y); o.z = f2bf(v.z); o.w = f2bf(v.w);
    ((ushort4*)Wob)[i] = o;
  } else {                                // bc: 2*16*512
    int i = (bid - 8448) * 256 + tid;
    int l = i >> 13, j = i & 511;
    bc[i] = bs[l * 512 + j] + br[i];
  }
}

// ---- one GEMM phase: A from LDS h, B global->reg, barrier-free ----
// C[64][NT] = h[64][KK] * W[NT][KK]^T (+bias)(+resid)(relu), in-place into h
// unless F32OUT. 8 waves; wave w owns cols [w*NC,(w+1)*NC), all 64 rows.
template <int NT, int KK, int RESID, int F32OUT>
static __device__ __forceinline__ void gemm_phase(
    const uint16_t* __restrict__ W, const float* __restrict__ bias,
    uint16_t* h, float* __restrict__ gout) {
  constexpr int NSTEP = KK / 32;
  constexpr int NC = NT / 8;          // 64 or 32 cols per wave
  constexpr int NFRAG = NC / 16;      // 4 or 2

  const int tid = threadIdx.x;
  const int lane = tid & 63, wave = tid >> 6;
  const int lr = lane & 15, c0 = lane >> 4;
  const int rb = c0 * 4;

  // B source: lane (lr,c0), frag n, step t ->
  //   W[(wave*NC + n*16 + lr)*KK + t*32 + c0*8], 16B (16 x 64B segs/instr)
  const uint16_t* wb = W + (size_t)(wave * NC + lr) * KK + c0 * 8;

  bf16x8 a[2][4], b[2][NFRAG];

  auto issue_b = [&](int slot, int t) {
    #pragma unroll
    for (int n = 0; n < NFRAG; n++)
      b[slot][n] = *(const bf16x8*)(wb + (size_t)n * 16 * KK + t * 32);
  };

  issue_b(0, 0);
  issue_b(1, 1);

  // acc init = bias (+ residual from h) — hides under first b latency
  f32x4 acc[4][NFRAG];
  #pragma unroll
  for (int n = 0; n < NFRAG; n++) {
    const int col = wave * NC + n * 16 + lr;
    const float bv = bias[col];
    #pragma unroll
    for (int m = 0; m < 4; m++)
      #pragma unroll
      for (int r = 0; r < 4; r++) {
        float v = bv;
        if constexpr (RESID)
          v += bf2f(h[(size_t)(m * 16 + rb + r) * HPAD + col]);
        acc[m][n][r] = v;
      }
  }

  const uint16_t* pA0 = h + (size_t)lr * HPAD + c0 * 8;

  auto read_a = [&](int slot, int t) {
    #pragma unroll
    for (int m = 0; m < 4; m++)
      a[slot][m] = *(const bf16x8*)(pA0 + (size_t)m * 16 * HPAD + t * 32);
  };

  read_a(0, 0);
  if constexpr (NFRAG == 4) { VMWAIT(4); } else { VMWAIT(2); }  // b(0) landed

  #pragma unroll
  for (int t = 0; t < NSTEP; t++) {
    const int cur = t & 1, nxt = cur ^ 1;
    if (t + 1 < NSTEP) read_a(nxt, t + 1);   // ds_read under MFMA(t)
    __builtin_amdgcn_s_setprio(1);
    #pragma unroll
    for (int m = 0; m < 4; m++)
      #pragma unroll
      for (int n = 0; n < NFRAG; n++)
        acc[m][n] = __builtin_amdgcn_mfma_f32_16x16x32_bf16(
            a[cur][m], b[cur][n], acc[m][n], 0, 0, 0);
    __builtin_amdgcn_s_setprio(0);
    if (t + 2 < NSTEP) issue_b(cur, t + 2);  // refill just-consumed slot
    if (t + 1 < NSTEP) {
      // ensure b(t+1) landed: if b(t+2) was issued, NFRAG newest may remain
      if (t + 2 < NSTEP) {
        if constexpr (NFRAG == 4) { VMWAIT(4); } else { VMWAIT(2); }
      } else {
        VMWAIT(0);
      }
    }
  }

  // ---- epilogue ----
  if constexpr (F32OUT) {
    #pragma unroll
    for (int n = 0; n < NFRAG; n++) {
      const int col = wave * NC + n * 16 + lr;
      #pragma unroll
      for (int m = 0; m < 4; m++)
        #pragma unroll
        for (int r = 0; r < 4; r++)
          gout[(size_t)(m * 16 + rb + r) * 256 + col] = acc[m][n][r];
    }
  } else {
    __syncthreads();  // all waves done reading h (A + resid)
    #pragma unroll
    for (int n = 0; n < NFRAG; n++) {
      const int col = wave * NC + n * 16 + lr;
      #pragma unroll
      for (int m = 0; m < 4; m++)
        #pragma unroll
        for (int r = 0; r < 4; r++)
          h[(size_t)(m * 16 + rb + r) * HPAD + col] =
              f2bf(fmaxf(acc[m][n][r], 0.0f));
    }
    __syncthreads();  // writes visible before next phase reads
  }
}

__global__ __launch_bounds__(512) void k_fused(
    const float* __restrict__ x, const int* __restrict__ route,
    const uint16_t* __restrict__ Wib, const float* __restrict__ bi,
    const uint16_t* __restrict__ Wcb, const float* __restrict__ bcb,
    const uint16_t* __restrict__ Wob, const float* __restrict__ bo,
    float* __restrict__ out) {
  __shared__ uint16_t h[64 * HPAD];     // 66,560 B total LDS

  const int tid = threadIdx.x;
  // XCD swizzle: XCD r (= bid%8) gets the 8 batches with batch%8==r
  // (4 slabs each) -> per-phase L2 weight set <= 4MB (fits).
  const int bid = blockIdx.x;
  const int r = bid & 7, q = bid >> 3;
  const int batch = (q >> 2) * 8 + r;   // 0..63
  const int bx = batch * 4 + (q & 3);   // slab id 0..255
  const int e = route[batch];

  // stage x slab f32 -> bf16 into h (coalesced float4)  [proven R5-R8]
  const float* gx = x + (size_t)bx * 16384;
  #pragma unroll
  for (int j = 0; j < 8; j++) {
    int fi = j * 2048 + tid * 4;
    float4 v = *(const float4*)(gx + fi);
    int row = fi >> 8, c = fi & 255;
    ushort4 o;
    o.x = f2bf(v.x); o.y = f2bf(v.y); o.z = f2bf(v.z); o.w = f2bf(v.w);
    *(ushort4*)(h + (size_t)row * HPAD + c) = o;
  }
  __syncthreads();

  // proj: h = relu(x * Wi^T + bi)            N=512 K=256
  gemm_phase<512, 256, 0, 0>(Wib, bi, h, nullptr);
  // layer 0: h = relu(h*Wc[0,e]^T + bc + h)  N=K=512
  gemm_phase<512, 512, 1, 0>(Wcb + (size_t)e * 262144, bcb + e * 512,
                             h, nullptr);
  // layer 1
  gemm_phase<512, 512, 1, 0>(Wcb + (size_t)(16 + e) * 262144,
                             bcb + (16 + e) * 512, h, nullptr);
  // out: f32 = h * Wo^T + bo                 N=256 K=512
  gemm_phase<256, 512, 0, 1>(Wob, bo, h, out + (size_t)bx * 16384);
}

extern "C" void kernel_launch(void* const* d_in, const int* in_sizes, int n_in,
                              void* d_out, int out_size, void* d_ws, size_t ws_size,
                              hipStream_t stream) {
  const float* x     = (const float*)d_in[0];
  const int*   route = (const int*)d_in[1];
  const float* Wi    = (const float*)d_in[2];
  const float* bi    = (const float*)d_in[3];
  const float* Wr    = (const float*)d_in[4];
  const float* br    = (const float*)d_in[5];
  const float* Ws    = (const float*)d_in[6];
  const float* bs    = (const float*)d_in[7];
  const float* Wo    = (const float*)d_in[8];
  const float* bo    = (const float*)d_in[9];

  char* ws = (char*)d_ws;
  uint16_t* Wib = (uint16_t*)(ws);                  //    262,144 B
  uint16_t* Wcb = (uint16_t*)(ws + 262144);         // 16,777,216 B
  uint16_t* Wob = (uint16_t*)(ws + 17039360);       //    262,144 B
  float*    bc  = (float*)   (ws + 17301504);       //     65,536 B

  k_prep<<<8512, 256, 0, stream>>>(Ws, Wr, Wi, Wo, bs, br,
                                   Wcb, Wib, Wob, bc);
  k_fused<<<256, 512, 0, stream>>>(x, route, Wib, bi, Wcb, bc, Wob, bo,
                                   (float*)d_out);
}

// Round 13
// 68.693 us; speedup vs baseline: 1.0014x; 1.0014x over previous
//
#include <hip/hip_runtime.h>
#include <hip/hip_bf16.h>
#include <stdint.h>

// MoEDecoder: B=64,T=256,IN=256,HID=512,OUT=256,L=2,E=16,S=1
// R13: B direct-to-register via INLINE-ASM global_load_dwordx4 (forced
// resident double-buffer; R6/R12's plain-C++ version let the compiler sink
// the loads -> VGPR 76 -> serial latency). LDS holds only h (A, 8x reuse).
// Counted vmcnt + sched_barrier(0) fences (rule 18). 8 waves, 64-token slab,
// grid 256, barrier-free K-loop, XCD swizzle, prep pass unchanged.

typedef __attribute__((ext_vector_type(8))) short bf16x8;
typedef __attribute__((ext_vector_type(4))) float f32x4;

#define HPAD 520  // h row stride: 1040B -> 4-bank row stagger, 2-way (free)
#define VMWAIT(N) asm volatile("s_waitcnt vmcnt(" #N ")" ::: "memory")

static __device__ __forceinline__ uint16_t f2bf(float f) {
  union { float f; uint32_t u; } c; c.f = f;
  uint32_t r = (c.u + 0x7FFFu + ((c.u >> 16) & 1u)) >> 16;
  return (uint16_t)r;
}
static __device__ __forceinline__ float bf2f(uint16_t h) {
  union { uint32_t u; float f; } c; c.u = ((uint32_t)h) << 16;
  return c.f;
}

// forced-register 16B global load (increments vmcnt; result valid after wait)
static __device__ __forceinline__ void gload16(bf16x8& dst,
                                               const uint16_t* addr) {
  asm volatile("global_load_dwordx4 %0, %1, off" : "=v"(dst) : "v"(addr));
}

// ---- merged pre-pass: Wc=Ws+Wr (bf16), Wi/Wo bf16, bc=bs+br ----
__global__ __launch_bounds__(256) void k_prep(
    const float* __restrict__ Ws, const float* __restrict__ Wr,
    const float* __restrict__ Wi, const float* __restrict__ Wo,
    const float* __restrict__ bs, const float* __restrict__ br,
    uint16_t* __restrict__ Wcb, uint16_t* __restrict__ Wib,
    uint16_t* __restrict__ Wob, float* __restrict__ bc) {
  int bid = blockIdx.x, tid = threadIdx.x;
  if (bid < 8192) {                       // combine_w: 2*16*512*512 / 4
    int i = bid * 256 + tid;
    int idx = i * 4;
    int l = idx >> 22;
    int within = idx & (262144 - 1);
    float4 a = *(const float4*)(Ws + l * 262144 + within);
    float4 b = *(const float4*)(Wr + idx);
    ushort4 o;
    o.x = f2bf(a.x + b.x); o.y = f2bf(a.y + b.y);
    o.z = f2bf(a.z + b.z); o.w = f2bf(a.w + b.w);
    ((ushort4*)Wcb)[i] = o;
  } else if (bid < 8320) {                // Wi: 512*256/4
    int i = (bid - 8192) * 256 + tid;
    float4 v = ((const float4*)Wi)[i];
    ushort4 o;
    o.x = f2bf(v.x); o.y = f2bf(v.y); o.z = f2bf(v.z); o.w = f2bf(v.w);
    ((ushort4*)Wib)[i] = o;
  } else if (bid < 8448) {                // Wo: 256*512/4
    int i = (bid - 8320) * 256 + tid;
    float4 v = ((const float4*)Wo)[i];
    ushort4 o;
    o.x = f2bf(v.x); o.y = f2bf(v.y); o.z = f2bf(v.z); o.w = f2bf(v.w);
    ((ushort4*)Wob)[i] = o;
  } else {                                // bc: 2*16*512
    int i = (bid - 8448) * 256 + tid;
    int l = i >> 13, j = i & 511;
    bc[i] = bs[l * 512 + j] + br[i];
  }
}

// ---- one GEMM phase: A from LDS h, B asm-loaded to regs, barrier-free ----
// C[64][NT] = h[64][KK] * W[NT][KK]^T (+bias)(+resid)(relu), in-place into h
// unless F32OUT. 8 waves; wave w owns cols [w*NC,(w+1)*NC), all 64 rows.
template <int NT, int KK, int RESID, int F32OUT>
static __device__ __forceinline__ void gemm_phase(
    const uint16_t* __restrict__ W, const float* __restrict__ bias,
    uint16_t* h, float* __restrict__ gout) {
  constexpr int NSTEP = KK / 32;
  constexpr int NC = NT / 8;          // 64 or 32 cols per wave
  constexpr int NFRAG = NC / 16;      // 4 or 2

  const int tid = threadIdx.x;
  const int lane = tid & 63, wave = tid >> 6;
  const int lr = lane & 15, c0 = lane >> 4;
  const int rb = c0 * 4;

  // B source: lane (lr,c0), frag n, step t ->
  //   W[(wave*NC + n*16 + lr)*KK + t*32 + c0*8], 16B
  const uint16_t* wb = W + (size_t)(wave * NC + lr) * KK + c0 * 8;

  bf16x8 a[2][4], b[2][NFRAG];

  auto issue_b = [&](int slot, int t) {
    #pragma unroll
    for (int n = 0; n < NFRAG; n++)
      gload16(b[slot][n], wb + (size_t)n * 16 * KK + t * 32);
  };

  issue_b(0, 0);
  issue_b(1, 1);

  // acc init = bias (+ residual from h) — hides under first b latency
  f32x4 acc[4][NFRAG];
  #pragma unroll
  for (int n = 0; n < NFRAG; n++) {
    const int col = wave * NC + n * 16 + lr;
    const float bv = bias[col];
    #pragma unroll
    for (int m = 0; m < 4; m++)
      #pragma unroll
      for (int r = 0; r < 4; r++) {
        float v = bv;
        if constexpr (RESID)
          v += bf2f(h[(size_t)(m * 16 + rb + r) * HPAD + col]);
        acc[m][n][r] = v;
      }
  }

  const uint16_t* pA0 = h + (size_t)lr * HPAD + c0 * 8;

  auto read_a = [&](int slot, int t) {
    #pragma unroll
    for (int m = 0; m < 4; m++)
      a[slot][m] = *(const bf16x8*)(pA0 + (size_t)m * 16 * HPAD + t * 32);
  };

  read_a(0, 0);
  // b(0) landed when only b(1)'s NFRAG remain outstanding
  if constexpr (NFRAG == 4) { VMWAIT(4); } else { VMWAIT(2); }
  __builtin_amdgcn_sched_barrier(0);

  #pragma unroll
  for (int t = 0; t < NSTEP; t++) {
    const int cur = t & 1, nxt = cur ^ 1;
    if (t + 1 < NSTEP) read_a(nxt, t + 1);   // ds_read under MFMA(t)
    __builtin_amdgcn_s_setprio(1);
    #pragma unroll
    for (int m = 0; m < 4; m++)
      #pragma unroll
      for (int n = 0; n < NFRAG; n++)
        acc[m][n] = __builtin_amdgcn_mfma_f32_16x16x32_bf16(
            a[cur][m], b[cur][n], acc[m][n], 0, 0, 0);
    __builtin_amdgcn_s_setprio(0);
    if (t + 2 < NSTEP) issue_b(cur, t + 2);  // refill consumed slot (WAR-safe)
    if (t + 1 < NSTEP) {
      // guarantee b(t+1): if b(t+2) in flight, NFRAG newest may remain
      if (t + 2 < NSTEP) {
        if constexpr (NFRAG == 4) { VMWAIT(4); } else { VMWAIT(2); }
      } else {
        VMWAIT(0);
      }
      __builtin_amdgcn_sched_barrier(0);     // rule 18: pin MFMA after wait
    }
  }

  // ---- epilogue ----
  if constexpr (F32OUT) {
    #pragma unroll
    for (int n = 0; n < NFRAG; n++) {
      const int col = wave * NC + n * 16 + lr;
      #pragma unroll
      for (int m = 0; m < 4; m++)
        #pragma unroll
        for (int r = 0; r < 4; r++)
          gout[(size_t)(m * 16 + rb + r) * 256 + col] = acc[m][n][r];
    }
  } else {
    __syncthreads();  // all waves done reading h (A + resid)
    #pragma unroll
    for (int n = 0; n < NFRAG; n++) {
      const int col = wave * NC + n * 16 + lr;
      #pragma unroll
      for (int m = 0; m < 4; m++)
        #pragma unroll
        for (int r = 0; r < 4; r++)
          h[(size_t)(m * 16 + rb + r) * HPAD + col] =
              f2bf(fmaxf(acc[m][n][r], 0.0f));
    }
    __syncthreads();  // writes visible before next phase reads
  }
}

__global__ __launch_bounds__(512) void k_fused(
    const float* __restrict__ x, const int* __restrict__ route,
    const uint16_t* __restrict__ Wib, const float* __restrict__ bi,
    const uint16_t* __restrict__ Wcb, const float* __restrict__ bcb,
    const uint16_t* __restrict__ Wob, const float* __restrict__ bo,
    float* __restrict__ out) {
  __shared__ uint16_t h[64 * HPAD];     // 66,560 B total LDS

  const int tid = threadIdx.x;
  // XCD swizzle: XCD r (= bid%8) gets the 8 batches with batch%8==r
  // (4 slabs each) -> per-phase L2 weight set <= 4MB (fits).
  const int bid = blockIdx.x;
  const int r = bid & 7, q = bid >> 3;
  const int batch = (q >> 2) * 8 + r;   // 0..63
  const int bx = batch * 4 + (q & 3);   // slab id 0..255
  const int e = route[batch];

  // stage x slab f32 -> bf16 into h (coalesced float4)  [proven R5-R8]
  const float* gx = x + (size_t)bx * 16384;
  #pragma unroll
  for (int j = 0; j < 8; j++) {
    int fi = j * 2048 + tid * 4;
    float4 v = *(const float4*)(gx + fi);
    int row = fi >> 8, c = fi & 255;
    ushort4 o;
    o.x = f2bf(v.x); o.y = f2bf(v.y); o.z = f2bf(v.z); o.w = f2bf(v.w);
    *(ushort4*)(h + (size_t)row * HPAD + c) = o;
  }
  __syncthreads();

  // proj: h = relu(x * Wi^T + bi)            N=512 K=256
  gemm_phase<512, 256, 0, 0>(Wib, bi, h, nullptr);
  // layer 0: h = relu(h*Wc[0,e]^T + bc + h)  N=K=512
  gemm_phase<512, 512, 1, 0>(Wcb + (size_t)e * 262144, bcb + e * 512,
                             h, nullptr);
  // layer 1
  gemm_phase<512, 512, 1, 0>(Wcb + (size_t)(16 + e) * 262144,
                             bcb + (16 + e) * 512, h, nullptr);
  // out: f32 = h * Wo^T + bo                 N=256 K=512
  gemm_phase<256, 512, 0, 1>(Wob, bo, h, out + (size_t)bx * 16384);
}

extern "C" void kernel_launch(void* const* d_in, const int* in_sizes, int n_in,
                              void* d_out, int out_size, void* d_ws, size_t ws_size,
                              hipStream_t stream) {
  const float* x     = (const float*)d_in[0];
  const int*   route = (const int*)d_in[1];
  const float* Wi    = (const float*)d_in[2];
  const float* bi    = (const float*)d_in[3];
  const float* Wr    = (const float*)d_in[4];
  const float* br    = (const float*)d_in[5];
  const float* Ws    = (const float*)d_in[6];
  const float* bs    = (const float*)d_in[7];
  const float* Wo    = (const float*)d_in[8];
  const float* bo    = (const float*)d_in[9];

  char* ws = (char*)d_ws;
  uint16_t* Wib = (uint16_t*)(ws);                  //    262,144 B
  uint16_t* Wcb = (uint16_t*)(ws + 262144);         // 16,777,216 B
  uint16_t* Wob = (uint16_t*)(ws + 17039360);       //    262,144 B
  float*    bc  = (float*)   (ws + 17301504);       //     65,536 B

  k_prep<<<8512, 256, 0, stream>>>(Ws, Wr, Wi, Wo, bs, br,
                                   Wcb, Wib, Wob, bc);
  k_fused<<<256, 512, 0, stream>>>(x, route, Wib, bi, Wcb, bc, Wob, bo,
                                   (float*)d_out);
}